// Round 3
// baseline (631.208 us; speedup 1.0000x reference)
//
#include <hip/hip_runtime.h>

// ---------------------------------------------------------------------------
// GNNQNetwork hetero-GAT, MI355X fp32. Round 3: CSR-free two-pass edges.
//
// Pass A: per-edge softmax denominator via one float atomic into the dst
// record {ld, denom, batch}. Pass B: per-edge alpha*x accumulated into a
// per-block LDS copy of P[6][64][16] (+cntE slots), flushed to partials and
// reduced. Source features packed fp16 per node type (1 aligned line/edge).
// ---------------------------------------------------------------------------

constexpr int kNT = 100000, kNRV = 200000, kNR = 300000, kE = 400000;
constexpr int kTOTE   = 6 * kE;          // 2,400,000 edges
constexpr int kTOTD   = 1200000;         // concatenated dst records
constexpr int kNITEMS = kTOTE + kTOTD;   // passB grid-stride domain
constexpr int kPSZ    = 6528;            // 6*64*16 acc + 6*64 cntE

// workspace offsets in 4-byte units
constexpr long long OFF_C    = 0;        // 6*2176 floats: C rows + cb@2048
constexpr long long OFF_VS   = 13056;    // 6*20
constexpr long long OFF_VD   = 13176;    // 6*20
constexpr long long OFF_LS   = 13296;    // 1,200,000 src logits (per et)
constexpr long long OFF_DR   = 1213296;  // 1,200,000 float4 dst recs
constexpr long long OFF_XR   = 6013296;  // 5,200,000 halves (2.6M floats)
constexpr long long OFF_P    = 8613296;  // kPSZ
constexpr long long OFF_XCAT = 8619824;  // 64*512
constexpr long long OFF_PB   = 8652592;  // nPB * kPSZ (flex, sized from ws)

// ls float bases per et (indexed by src node id):   src types rv,t,r,rv,t,r
// dr rec  bases per et (indexed by dst node id):    dst types t,rv,rv,r,r,t
// xr half bases per src type: tile 0 (8h/rec), rv 800000 (16h/rec), road 4000000 (4h/rec)

// ---------------------------------------------------------------------------
__global__ __launch_bounds__(256) void precompute_kernel(
    const float* encW_t, const float* encb_t,
    const float* encW_rv, const float* encb_rv,
    const float* encW_r, const float* encb_r,
    const float* W0, const float* as0, const float* ad0,
    const float* W1, const float* as1, const float* ad1,
    const float* W2, const float* as2, const float* ad2,
    const float* W3, const float* as3, const float* ad3,
    const float* W4, const float* as4, const float* ad4,
    const float* W5, const float* as5, const float* ad5,
    float* Cws, float* vsw, float* vdw)
{
  const float* encW[3] = {encW_t, encW_rv, encW_r};
  const float* encb[3] = {encb_t, encb_rv, encb_r};
  const int    Ks[3]   = {8, 13, 4};
  const float* Wv[6]  = {W0, W1, W2, W3, W4, W5};
  const float* asv[6] = {as0, as1, as2, as3, as4, as5};
  const float* adv[6] = {ad0, ad1, ad2, ad3, ad4, ad5};
  const int srcT[6] = {1, 0, 2, 1, 0, 2};
  const int dstT[6] = {0, 1, 1, 2, 2, 0};

  __shared__ float Cl[2176];
  __shared__ float wv[128];

  int et = blockIdx.x;
  int tid = threadIdx.x;
  int st = srcT[et], dt = dstT[et];
  const float* eW = encW[st];
  const float* eB = encb[st];
  int K = Ks[st];
  const float* W = Wv[et];
  const float* a_s = asv[et];
  const float* a_d = adv[et];
  float* Cslot = Cws + et * 2176;

  for (int idx = tid; idx < (K + 1) * 128; idx += 256) {
    int r = idx >> 7, j = idx & 127;
    const float* row = (r < K) ? (eW + r * 128) : eB;
    float acc = 0.f;
    for (int m = 0; m < 128; ++m) acc += row[m] * W[m * 128 + j];
    int o = (r < K) ? (r * 128 + j) : (2048 + j);
    Cl[o] = acc;
    Cslot[o] = acc;
  }
  if (tid < 128) {
    float acc = 0.f;
    for (int j = 0; j < 128; ++j) acc += W[tid * 128 + j] * a_d[j];
    wv[tid] = acc;
  }
  __syncthreads();
  if (tid <= K) {
    const float* row = (tid < K) ? (Cl + tid * 128) : (Cl + 2048);
    float acc = 0.f;
    for (int j = 0; j < 128; ++j) acc += row[j] * a_s[j];
    vsw[et * 20 + (tid < K ? tid : 16)] = acc;
  }
  int KD = Ks[dt];
  if (tid >= 32 && tid <= 32 + KD) {
    int k = tid - 32;
    const float* row = (k < KD) ? (encW[dt] + k * 128) : encb[dt];
    float acc = 0.f;
    for (int m = 0; m < 128; ++m) acc += row[m] * wv[m];
    vdw[et * 20 + (k < KD ? k : 16)] = acc;
  }
}

// ---------------------------------------------------------------------------
template <int K, int RH>
__device__ __forceinline__ void prep_one(
    const float* __restrict__ xr, float bf,
    const float* __restrict__ vsA, const float* __restrict__ vsB,
    const float* __restrict__ vdA, const float* __restrict__ vdB,
    float* lsA, float* lsB, float4* drA, float4* drB, _Float16* xrec)
{
  float a0 = 0.f, a1 = 0.f, a2 = 0.f, a3 = 0.f;
#pragma unroll
  for (int k = 0; k < K; ++k) {
    float xv = xr[k];
    a0 += xv * vsA[k]; a1 += xv * vsB[k];
    a2 += xv * vdA[k]; a3 += xv * vdB[k];
    xrec[k] = (_Float16)xv;
  }
#pragma unroll
  for (int k = K; k < RH; ++k) xrec[k] = (_Float16)0.f;
  *lsA = a0 + vsA[16];
  *lsB = a1 + vsB[16];
  *drA = make_float4(a2 + vdA[16], 0.f, bf, 0.f);
  *drB = make_float4(a3 + vdB[16], 0.f, bf, 0.f);
}

__global__ __launch_bounds__(256) void prep_kernel(
    const float* __restrict__ x_t, const float* __restrict__ x_rv,
    const float* __restrict__ x_r,
    const int* __restrict__ bt, const int* __restrict__ brv,
    const int* __restrict__ br,
    const float* __restrict__ vsw, const float* __restrict__ vdw,
    float* __restrict__ LS, float4* __restrict__ DR, _Float16* __restrict__ XR)
{
  int n = blockIdx.x * 256 + threadIdx.x;
  if (n >= kNT + kNRV + kNR) return;
  if (n < kNT) {
    // tile: src roles et1,et4 (K=8); dst roles et0,et5
    prep_one<8, 8>(x_t + n * 8, (float)bt[n],
                   vsw + 1 * 20, vsw + 4 * 20, vdw + 0 * 20, vdw + 5 * 20,
                   LS + 200000 + n, LS + 800000 + n,
                   DR + 0 + n, DR + 1100000 + n,
                   XR + (long long)n * 8);
  } else if (n < kNT + kNRV) {
    int m = n - kNT;
    // rv: src roles et0,et3 (K=13); dst roles et1,et2
    prep_one<13, 16>(x_rv + m * 13, (float)brv[m],
                     vsw + 0 * 20, vsw + 3 * 20, vdw + 1 * 20, vdw + 2 * 20,
                     LS + 0 + m, LS + 600000 + m,
                     DR + 100000 + m, DR + 300000 + m,
                     XR + 800000 + (long long)m * 16);
  } else {
    int m = n - kNT - kNRV;
    // road: src roles et2,et5 (K=4); dst roles et3,et4
    prep_one<4, 4>(x_r + m * 4, (float)br[m],
                   vsw + 2 * 20, vsw + 5 * 20, vdw + 3 * 20, vdw + 4 * 20,
                   LS + 300000 + m, LS + 900000 + m,
                   DR + 500000 + m, DR + 800000 + m,
                   XR + 4000000 + (long long)m * 4);
  }
}

// ---------------------------------------------------------------------------
__global__ __launch_bounds__(256) void passA_kernel(
    const int* s0, const int* s1, const int* s2,
    const int* s3, const int* s4, const int* s5,
    const int* d0, const int* d1, const int* d2,
    const int* d3, const int* d4, const int* d5,
    const float* __restrict__ LS, float* __restrict__ DRf)
{
  int i = blockIdx.x * 256 + threadIdx.x;
  if (i >= kTOTE) return;
  int et = i / kE;
  int e = i - et * kE;
  const int* sp; const int* dp; int lsb, drb;
  switch (et) {
    case 0: sp = s0; dp = d0; lsb = 0;      drb = 0;       break;
    case 1: sp = s1; dp = d1; lsb = 200000; drb = 100000;  break;
    case 2: sp = s2; dp = d2; lsb = 300000; drb = 300000;  break;
    case 3: sp = s3; dp = d3; lsb = 600000; drb = 500000;  break;
    case 4: sp = s4; dp = d4; lsb = 800000; drb = 800000;  break;
    default: sp = s5; dp = d5; lsb = 900000; drb = 1100000; break;
  }
  int s = sp[e], d = dp[e];
  float t = LS[lsb + s] + DRf[(drb + d) * 4];
  t = t > 0.f ? t : 0.2f * t;
  unsafeAtomicAdd(&DRf[(drb + d) * 4 + 1], __expf(t));
}

// ---------------------------------------------------------------------------
template <int K, int RH>
__device__ __forceinline__ void edgeB(
    int e, const int* __restrict__ sp, const int* __restrict__ dp,
    const float* __restrict__ LS, int lsb,
    const float4* __restrict__ DR, int drb,
    const _Float16* __restrict__ XR, long long xrb, int et, float* lp)
{
  int s = sp[e], d = dp[e];
  float4 rec = DR[drb + d];
  float t = LS[lsb + s] + rec.x;
  t = t > 0.f ? t : 0.2f * t;
  float alpha = __expf(t) / fmaxf(rec.y, 1e-16f);
  int b = (int)rec.z;
  float* slot = lp + ((et << 6) + b) * 16;
  const _Float16* xp = XR + xrb + (long long)s * RH;
  float xv[K];
  if constexpr (RH == 4) {
    union { uint2 u; _Float16 h[4]; } U;
    U.u = *(const uint2*)xp;
#pragma unroll
    for (int k = 0; k < K; ++k) xv[k] = (float)U.h[k];
  } else if constexpr (RH == 8) {
    union { uint4 u; _Float16 h[8]; } U;
    U.u = *(const uint4*)xp;
#pragma unroll
    for (int k = 0; k < K; ++k) xv[k] = (float)U.h[k];
  } else {
    union { uint4 u[2]; _Float16 h[16]; } U;
    U.u[0] = *(const uint4*)xp;
    U.u[1] = *(const uint4*)(xp + 8);
#pragma unroll
    for (int k = 0; k < K; ++k) xv[k] = (float)U.h[k];
  }
#pragma unroll
  for (int k = 0; k < K; ++k) atomicAdd(slot + k, alpha * xv[k]);
}

__global__ __launch_bounds__(256) void passB_kernel(
    const int* s0, const int* s1, const int* s2,
    const int* s3, const int* s4, const int* s5,
    const int* d0, const int* d1, const int* d2,
    const int* d3, const int* d4, const int* d5,
    const float* __restrict__ LS, const float4* __restrict__ DR,
    const _Float16* __restrict__ XR, float* __restrict__ PB, int stride)
{
  __shared__ float lp[kPSZ];
  for (int j = threadIdx.x; j < kPSZ; j += 256) lp[j] = 0.f;
  __syncthreads();
  for (int i = blockIdx.x * 256 + threadIdx.x; i < kNITEMS; i += stride) {
    if (i < kTOTE) {
      int et = i / kE;
      int e = i - et * kE;
      switch (et) {
        case 0: edgeB<13,16>(e, s0, d0, LS, 0,      DR, 0,       XR, 800000,  0, lp); break;
        case 1: edgeB< 8, 8>(e, s1, d1, LS, 200000, DR, 100000,  XR, 0,       1, lp); break;
        case 2: edgeB< 4, 4>(e, s2, d2, LS, 300000, DR, 300000,  XR, 4000000, 2, lp); break;
        case 3: edgeB<13,16>(e, s3, d3, LS, 600000, DR, 500000,  XR, 800000,  3, lp); break;
        case 4: edgeB< 8, 8>(e, s4, d4, LS, 800000, DR, 800000,  XR, 0,       4, lp); break;
        default: edgeB<4, 4>(e, s5, d5, LS, 900000, DR, 1100000, XR, 4000000, 5, lp); break;
      }
    } else {
      // cntE: count dst nodes with >=1 edge, per (et, batch)
      int j = i - kTOTE;            // DR is laid out contiguously in et order
      float4 rec = DR[j];
      if (rec.y > 0.f) {
        int et = (j < 100000) ? 0 : (j < 300000) ? 1 : (j < 500000) ? 2
               : (j < 800000) ? 3 : (j < 1100000) ? 4 : 5;
        atomicAdd(lp + 6144 + (et << 6) + (int)rec.z, 1.f);
      }
    }
  }
  __syncthreads();
  float* dst = PB + (long long)blockIdx.x * kPSZ;
  for (int j = threadIdx.x; j < kPSZ; j += 256) dst[j] = lp[j];
}

// ---------------------------------------------------------------------------
__global__ __launch_bounds__(256) void reduceP_kernel(
    const float* __restrict__ PB, float* __restrict__ P, int nblocks)
{
  int j = blockIdx.x * 256 + threadIdx.x;
  if (j >= kPSZ) return;
  float s = 0.f;
  for (int b = 0; b < nblocks; ++b) s += PB[(long long)b * kPSZ + j];
  P[j] = s;
}

// ---------------------------------------------------------------------------
__device__ __forceinline__ int lowb(const int* a, int n, int v) {
  int lo = 0, hi = n;
  while (lo < hi) { int mid = (lo + hi) >> 1; if (a[mid] < v) lo = mid + 1; else hi = mid; }
  return lo;
}

__global__ __launch_bounds__(128) void finalize_kernel(
    const int* __restrict__ bt, const int* __restrict__ brv, const int* __restrict__ br,
    const float* __restrict__ xp,
    const float* __restrict__ fc1W, const float* __restrict__ fc1b,
    const float* __restrict__ fc2W, const float* __restrict__ fc2b,
    const float* __restrict__ b_rv2t, const float* __restrict__ b_r2t,
    const float* __restrict__ b_t2rv, const float* __restrict__ b_r2rv,
    const float* __restrict__ b_rv2r, const float* __restrict__ b_t2r,
    const float* __restrict__ Cws, const float* __restrict__ P,
    float* __restrict__ xcat)
{
  int b = blockIdx.x, tid = threadIdx.x;
  __shared__ float xps[64];
  __shared__ float p1s[128];
  __shared__ int cnts[3];
  if (tid < 64) xps[tid] = xp[b * 64 + tid];
  if (tid < 3) {
    const int* ba = (tid == 0) ? bt : (tid == 1 ? brv : br);
    int N = (tid == 0) ? kNT : (tid == 1 ? kNRV : kNR);
    cnts[tid] = lowb(ba, N, b + 1) - lowb(ba, N, b);
  }
  __syncthreads();
  float a = fc1b[tid];
  for (int k = 0; k < 64; ++k) a += xps[k] * fc1W[k * 128 + tid];
  p1s[tid] = fmaxf(a, 0.f);
  __syncthreads();
  float a2 = fc2b[tid];
  for (int k = 0; k < 128; ++k) a2 += p1s[k] * fc2W[k * 128 + tid];
  xcat[b * 512 + 384 + tid] = fmaxf(a2, 0.f);
  const int etA[3] = {0, 1, 3}, etB[3] = {5, 2, 4};
  const int KAv[3] = {13, 8, 13}, KBv[3] = {4, 4, 8};
  for (int t3 = 0; t3 < 3; ++t3) {
    int eA = etA[t3], eB = etB[t3];
    const float* CA = Cws + eA * 2176;
    const float* CB = Cws + eB * 2176;
    const float* pA = P + ((eA << 6) + b) * 16;
    const float* pB = P + ((eB << 6) + b) * 16;
    float cA = P[6144 + (eA << 6) + b];
    float cB = P[6144 + (eB << 6) + b];
    float v = cA * CA[2048 + tid] + cB * CB[2048 + tid];
    for (int k = 0; k < KAv[t3]; ++k) v += pA[k] * CA[k * 128 + tid];
    for (int k = 0; k < KBv[t3]; ++k) v += pB[k] * CB[k * 128 + tid];
    float cnt = (float)max(cnts[t3], 1);
    const float* bb1 = (t3 == 0) ? b_rv2t : (t3 == 1 ? b_t2rv : b_rv2r);
    const float* bb2 = (t3 == 0) ? b_r2t  : (t3 == 1 ? b_r2rv : b_t2r);
    xcat[b * 512 + t3 * 128 + tid] = v / cnt + bb1[tid] + bb2[tid];
  }
}

// ---------------------------------------------------------------------------
__global__ __launch_bounds__(256) void out_kernel(
    const float* __restrict__ xcat, const float* __restrict__ outW,
    const float* __restrict__ outb, float* __restrict__ out)
{
  int g = blockIdx.x * 256 + threadIdx.x;   // 64*512
  int r = g >> 9, c = g & 511;
  const float* xr = xcat + r * 512;
  float acc = outb[c];
  for (int k = 0; k < 512; ++k) acc += xr[k] * outW[k * 512 + c];
  out[g] = acc;
}

// ---------------------------------------------------------------------------
extern "C" void kernel_launch(void* const* d_in, const int* in_sizes, int n_in,
                              void* d_out, int out_size, void* d_ws, size_t ws_size,
                              hipStream_t stream) {
  const float* x_tile   = (const float*)d_in[0];
  const float* x_rv     = (const float*)d_in[1];
  const float* x_road   = (const float*)d_in[2];
  const float* x_player = (const float*)d_in[3];
  const float* enc_t_W  = (const float*)d_in[4];
  const float* enc_t_b  = (const float*)d_in[5];
  const float* enc_rv_W = (const float*)d_in[6];
  const float* enc_rv_b = (const float*)d_in[7];
  const float* enc_r_W  = (const float*)d_in[8];
  const float* enc_r_b  = (const float*)d_in[9];
  const float* W[6]; const float* As[6]; const float* Ad[6]; const float* Bb[6];
  for (int et = 0; et < 6; ++et) {
    W[et]  = (const float*)d_in[10 + 4 * et];
    As[et] = (const float*)d_in[11 + 4 * et];
    Ad[et] = (const float*)d_in[12 + 4 * et];
    Bb[et] = (const float*)d_in[13 + 4 * et];
  }
  const float* fc1W = (const float*)d_in[34];
  const float* fc1b = (const float*)d_in[35];
  const float* fc2W = (const float*)d_in[36];
  const float* fc2b = (const float*)d_in[37];
  const float* outW = (const float*)d_in[38];
  const float* outb = (const float*)d_in[39];
  const int* esrc[6]; const int* edst[6];
  for (int et = 0; et < 6; ++et) {
    esrc[et] = (const int*)d_in[40 + 2 * et];
    edst[et] = (const int*)d_in[41 + 2 * et];
  }
  const int* batch_t  = (const int*)d_in[52];
  const int* batch_rv = (const int*)d_in[53];
  const int* batch_r  = (const int*)d_in[54];

  float* wsF = (float*)d_ws;
  float* Cws  = wsF + OFF_C;
  float* vsw  = wsF + OFF_VS;
  float* vdw  = wsF + OFF_VD;
  float* LS   = wsF + OFF_LS;
  float4* DR  = (float4*)(wsF + OFF_DR);
  float* DRf  = wsF + OFF_DR;
  _Float16* XR = (_Float16*)(wsF + OFF_XR);
  float* P    = wsF + OFF_P;
  float* xcat = wsF + OFF_XCAT;
  float* PB   = wsF + OFF_PB;
  float* out  = (float*)d_out;

  // PB block count adapts to workspace (constant across calls -> graph-safe)
  long long availF = (long long)(ws_size / 4) - OFF_PB;
  int nPB = (int)(availF / kPSZ);
  if (nPB > 512) nPB = 512;
  if (nPB < 16) nPB = 16;

  precompute_kernel<<<6, 256, 0, stream>>>(
      enc_t_W, enc_t_b, enc_rv_W, enc_rv_b, enc_r_W, enc_r_b,
      W[0], As[0], Ad[0], W[1], As[1], Ad[1], W[2], As[2], Ad[2],
      W[3], As[3], Ad[3], W[4], As[4], Ad[4], W[5], As[5], Ad[5],
      Cws, vsw, vdw);

  prep_kernel<<<(kNT + kNRV + kNR + 255) / 256, 256, 0, stream>>>(
      x_tile, x_rv, x_road, batch_t, batch_rv, batch_r, vsw, vdw, LS, DR, XR);

  passA_kernel<<<(kTOTE + 255) / 256, 256, 0, stream>>>(
      esrc[0], esrc[1], esrc[2], esrc[3], esrc[4], esrc[5],
      edst[0], edst[1], edst[2], edst[3], edst[4], edst[5], LS, DRf);

  passB_kernel<<<nPB, 256, 0, stream>>>(
      esrc[0], esrc[1], esrc[2], esrc[3], esrc[4], esrc[5],
      edst[0], edst[1], edst[2], edst[3], edst[4], edst[5],
      LS, DR, XR, PB, nPB * 256);

  reduceP_kernel<<<(kPSZ + 255) / 256, 256, 0, stream>>>(PB, P, nPB);

  finalize_kernel<<<64, 128, 0, stream>>>(
      batch_t, batch_rv, batch_r, x_player,
      fc1W, fc1b, fc2W, fc2b,
      Bb[0], Bb[5], Bb[1], Bb[2], Bb[3], Bb[4],
      Cws, P, xcat);

  out_kernel<<<128, 256, 0, stream>>>(xcat, outW, outb, out);

  (void)in_sizes; (void)n_in; (void)out_size;
}

// Round 4
// 506.715 us; speedup vs baseline: 1.2457x; 1.2457x over previous
//
#include <hip/hip_runtime.h>

// ---------------------------------------------------------------------------
// GNNQNetwork hetero-GAT, MI355X fp32. Round 4.
//
// passA: per-edge w=exp(leaky(ls+ld)) -> fp16 w[] (coalesced) + atomicAdd
//        into dense float2{denom,batch} records (8B apart, not 64B lines).
// passB: per-et block groups; per-edge alpha*x accumulated into a 1088-float
//        LDS tile laid out [k][64 batches] (bank = b%32, conflict-free);
//        2202 blocks, PB partials alias the dead LS/LD region.
// ---------------------------------------------------------------------------

constexpr int kNT = 100000, kNRV = 200000, kNR = 300000, kE = 400000;
constexpr int kTOTE = 6 * kE;      // 2,400,000 edges
constexpr int kSLOT = 1088;        // per-et P tile: 16x64 acc + 64 cnt
constexpr int kPSZ  = 6 * kSLOT;   // 6528
constexpr int kNB   = 367;         // passB blocks per edge type (PB-capacity)

// workspace offsets in 4-byte units (total 34.61 MB, proven footprint)
constexpr long long OFF_C    = 0;        // 6*2176: C rows + cb@2048
constexpr long long OFF_VS   = 13056;    // 6*20
constexpr long long OFF_VD   = 13176;    // 6*20
constexpr long long OFF_P    = 13296;    // kPSZ
constexpr long long OFF_XCAT = 19824;    // 64*512
constexpr long long OFF_LS   = 52592;    // 1.2M src logits (per-et bases)
constexpr long long OFF_LD   = 1252592;  // 1.2M dst logits (dense, drb bases)
constexpr long long OFF_PB   = 52592;    // aliases LS/LD after passA: 2202*1088
constexpr long long OFF_W16  = 2452592;  // 2.4M halves (1.2M floats)
constexpr long long OFF_DR2  = 3652592;  // 1.2M float2 {denom, batch}
constexpr long long OFF_XR   = 6052592;  // 5.2M halves (2.6M floats)
// end 8652592 floats = 34.61 MB

// per-et constant tables
// src type: rv,t,r,rv,t,r ; dst type: t,rv,rv,r,r,t
__constant__ const int kLSB[6] = {0, 200000, 300000, 600000, 800000, 900000};
__constant__ const int kDRB[6] = {0, 100000, 300000, 500000, 800000, 1100000};
__constant__ const int kDLEN[6] = {100000, 200000, 200000, 300000, 300000, 100000};

// ---------------------------------------------------------------------------
__global__ __launch_bounds__(256) void precompute_kernel(
    const float* encW_t, const float* encb_t,
    const float* encW_rv, const float* encb_rv,
    const float* encW_r, const float* encb_r,
    const float* W0, const float* as0, const float* ad0,
    const float* W1, const float* as1, const float* ad1,
    const float* W2, const float* as2, const float* ad2,
    const float* W3, const float* as3, const float* ad3,
    const float* W4, const float* as4, const float* ad4,
    const float* W5, const float* as5, const float* ad5,
    float* Cws, float* vsw, float* vdw)
{
  const float* encW[3] = {encW_t, encW_rv, encW_r};
  const float* encb[3] = {encb_t, encb_rv, encb_r};
  const int    Ks[3]   = {8, 13, 4};
  const float* Wv[6]  = {W0, W1, W2, W3, W4, W5};
  const float* asv[6] = {as0, as1, as2, as3, as4, as5};
  const float* adv[6] = {ad0, ad1, ad2, ad3, ad4, ad5};
  const int srcT[6] = {1, 0, 2, 1, 0, 2};
  const int dstT[6] = {0, 1, 1, 2, 2, 0};

  __shared__ float Cl[2176];
  __shared__ float wv[128];

  int et = blockIdx.x;
  int tid = threadIdx.x;
  int st = srcT[et], dt = dstT[et];
  const float* eW = encW[st];
  const float* eB = encb[st];
  int K = Ks[st];
  const float* W = Wv[et];
  const float* a_s = asv[et];
  const float* a_d = adv[et];
  float* Cslot = Cws + et * 2176;

  for (int idx = tid; idx < (K + 1) * 128; idx += 256) {
    int r = idx >> 7, j = idx & 127;
    const float* row = (r < K) ? (eW + r * 128) : eB;
    float acc = 0.f;
    for (int m = 0; m < 128; ++m) acc += row[m] * W[m * 128 + j];
    int o = (r < K) ? (r * 128 + j) : (2048 + j);
    Cl[o] = acc;
    Cslot[o] = acc;
  }
  if (tid < 128) {
    float acc = 0.f;
    for (int j = 0; j < 128; ++j) acc += W[tid * 128 + j] * a_d[j];
    wv[tid] = acc;
  }
  __syncthreads();
  if (tid <= K) {
    const float* row = (tid < K) ? (Cl + tid * 128) : (Cl + 2048);
    float acc = 0.f;
    for (int j = 0; j < 128; ++j) acc += row[j] * a_s[j];
    vsw[et * 20 + (tid < K ? tid : 16)] = acc;
  }
  int KD = Ks[dt];
  if (tid >= 32 && tid <= 32 + KD) {
    int k = tid - 32;
    const float* row = (k < KD) ? (encW[dt] + k * 128) : encb[dt];
    float acc = 0.f;
    for (int m = 0; m < 128; ++m) acc += row[m] * wv[m];
    vdw[et * 20 + (k < KD ? k : 16)] = acc;
  }
}

// ---------------------------------------------------------------------------
template <int K, int RH>
__device__ __forceinline__ void prep_one(
    const float* __restrict__ xr, float bf,
    const float* __restrict__ vsA, const float* __restrict__ vsB,
    const float* __restrict__ vdA, const float* __restrict__ vdB,
    float* lsA, float* lsB, float* ldA, float* ldB,
    float2* dr2A, float2* dr2B, _Float16* xrec)
{
  float a0 = 0.f, a1 = 0.f, a2 = 0.f, a3 = 0.f;
#pragma unroll
  for (int k = 0; k < K; ++k) {
    float xv = xr[k];
    a0 += xv * vsA[k]; a1 += xv * vsB[k];
    a2 += xv * vdA[k]; a3 += xv * vdB[k];
    xrec[k] = (_Float16)xv;
  }
#pragma unroll
  for (int k = K; k < RH; ++k) xrec[k] = (_Float16)0.f;
  *lsA = a0 + vsA[16];
  *lsB = a1 + vsB[16];
  *ldA = a2 + vdA[16];
  *ldB = a3 + vdB[16];
  *dr2A = make_float2(0.f, bf);
  *dr2B = make_float2(0.f, bf);
}

__global__ __launch_bounds__(256) void prep_kernel(
    const float* __restrict__ x_t, const float* __restrict__ x_rv,
    const float* __restrict__ x_r,
    const int* __restrict__ bt, const int* __restrict__ brv,
    const int* __restrict__ br,
    const float* __restrict__ vsw, const float* __restrict__ vdw,
    float* __restrict__ LS, float* __restrict__ LD,
    float2* __restrict__ DR2, _Float16* __restrict__ XR)
{
  int n = blockIdx.x * 256 + threadIdx.x;
  if (n >= kNT + kNRV + kNR) return;
  if (n < kNT) {
    // tile: src roles et1,et4 (K=8); dst roles et0,et5
    prep_one<8, 8>(x_t + n * 8, (float)bt[n],
                   vsw + 1 * 20, vsw + 4 * 20, vdw + 0 * 20, vdw + 5 * 20,
                   LS + 200000 + n, LS + 800000 + n,
                   LD + 0 + n, LD + 1100000 + n,
                   DR2 + 0 + n, DR2 + 1100000 + n,
                   XR + (long long)n * 8);
  } else if (n < kNT + kNRV) {
    int m = n - kNT;
    // rv: src roles et0,et3 (K=13); dst roles et1,et2
    prep_one<13, 16>(x_rv + m * 13, (float)brv[m],
                     vsw + 0 * 20, vsw + 3 * 20, vdw + 1 * 20, vdw + 2 * 20,
                     LS + 0 + m, LS + 600000 + m,
                     LD + 100000 + m, LD + 300000 + m,
                     DR2 + 100000 + m, DR2 + 300000 + m,
                     XR + 800000 + (long long)m * 16);
  } else {
    int m = n - kNT - kNRV;
    // road: src roles et2,et5 (K=4); dst roles et3,et4
    prep_one<4, 4>(x_r + m * 4, (float)br[m],
                   vsw + 2 * 20, vsw + 5 * 20, vdw + 3 * 20, vdw + 4 * 20,
                   LS + 300000 + m, LS + 900000 + m,
                   LD + 500000 + m, LD + 800000 + m,
                   DR2 + 500000 + m, DR2 + 800000 + m,
                   XR + 4000000 + (long long)m * 4);
  }
}

// ---------------------------------------------------------------------------
__global__ __launch_bounds__(256) void passA_kernel(
    const int* s0, const int* s1, const int* s2,
    const int* s3, const int* s4, const int* s5,
    const int* d0, const int* d1, const int* d2,
    const int* d3, const int* d4, const int* d5,
    const float* __restrict__ LS, const float* __restrict__ LD,
    float* __restrict__ DR2f, _Float16* __restrict__ W16)
{
  int i = blockIdx.x * 256 + threadIdx.x;
  if (i >= kTOTE) return;
  int et = i / kE;
  int e = i - et * kE;
  const int* sp; const int* dp;
  switch (et) {
    case 0: sp = s0; dp = d0; break;
    case 1: sp = s1; dp = d1; break;
    case 2: sp = s2; dp = d2; break;
    case 3: sp = s3; dp = d3; break;
    case 4: sp = s4; dp = d4; break;
    default: sp = s5; dp = d5; break;
  }
  int lsb = kLSB[et], drb = kDRB[et];
  int s = sp[e], d = dp[e];
  float t = LS[lsb + s] + LD[drb + d];
  t = t > 0.f ? t : 0.2f * t;
  _Float16 h = (_Float16)__expf(t);
  W16[i] = h;
  unsafeAtomicAdd(&DR2f[(long long)(drb + d) * 2], (float)h);
}

// ---------------------------------------------------------------------------
template <int K, int RH>
__device__ __forceinline__ void passB_loop(
    const int* __restrict__ sp, const int* __restrict__ dp,
    int drb, int dlen, long long xrb,
    const _Float16* __restrict__ W16et, const float2* __restrict__ DR2,
    const _Float16* __restrict__ XR, float* __restrict__ lp,
    int start, int stride)
{
  int nItems = kE + dlen;
  for (int i = start; i < nItems; i += stride) {
    if (i < kE) {
      int s = sp[i], d = dp[i];
      float2 rec = DR2[drb + d];
      float w = (float)W16et[i];
      float alpha = w / fmaxf(rec.x, 1e-16f);
      int b = (int)rec.y;
      const _Float16* xp = XR + xrb + (long long)s * RH;
      float xv[K];
      if constexpr (RH == 4) {
        union { uint2 u; _Float16 h[4]; } U;
        U.u = *(const uint2*)xp;
#pragma unroll
        for (int k = 0; k < K; ++k) xv[k] = (float)U.h[k];
      } else if constexpr (RH == 8) {
        union { uint4 u; _Float16 h[8]; } U;
        U.u = *(const uint4*)xp;
#pragma unroll
        for (int k = 0; k < K; ++k) xv[k] = (float)U.h[k];
      } else {
        union { uint4 u[2]; _Float16 h[16]; } U;
        U.u[0] = *(const uint4*)xp;
        U.u[1] = *(const uint4*)(xp + 8);
#pragma unroll
        for (int k = 0; k < K; ++k) xv[k] = (float)U.h[k];
      }
      // LDS tile [k][64 b-slots]: bank = b%32 -> <=2-way, free
#pragma unroll
      for (int k = 0; k < K; ++k) atomicAdd(lp + k * 64 + b, alpha * xv[k]);
    } else {
      int j = i - kE;
      float2 rec = DR2[drb + j];
      if (rec.x > 0.f) atomicAdd(lp + 1024 + (int)rec.y, 1.f);
    }
  }
}

__global__ __launch_bounds__(256) void passB_kernel(
    const int* s0, const int* s1, const int* s2,
    const int* s3, const int* s4, const int* s5,
    const int* d0, const int* d1, const int* d2,
    const int* d3, const int* d4, const int* d5,
    const _Float16* __restrict__ W16, const float2* __restrict__ DR2,
    const _Float16* __restrict__ XR, float* __restrict__ PB)
{
  __shared__ float lp[kSLOT];
  for (int j = threadIdx.x; j < kSLOT; j += 256) lp[j] = 0.f;
  __syncthreads();
  int et  = blockIdx.x / kNB;
  int blk = blockIdx.x - et * kNB;
  int start = blk * 256 + threadIdx.x;
  int stride = kNB * 256;
  int drb = kDRB[et], dlen = kDLEN[et];
  const _Float16* W16et = W16 + (long long)et * kE;
  switch (et) {
    case 0: passB_loop<13,16>(s0, d0, drb, dlen, 800000,  W16et, DR2, XR, lp, start, stride); break;
    case 1: passB_loop< 8, 8>(s1, d1, drb, dlen, 0,       W16et, DR2, XR, lp, start, stride); break;
    case 2: passB_loop< 4, 4>(s2, d2, drb, dlen, 4000000, W16et, DR2, XR, lp, start, stride); break;
    case 3: passB_loop<13,16>(s3, d3, drb, dlen, 800000,  W16et, DR2, XR, lp, start, stride); break;
    case 4: passB_loop< 8, 8>(s4, d4, drb, dlen, 0,       W16et, DR2, XR, lp, start, stride); break;
    default: passB_loop<4, 4>(s5, d5, drb, dlen, 4000000, W16et, DR2, XR, lp, start, stride); break;
  }
  __syncthreads();
  float* dst = PB + (long long)blockIdx.x * kSLOT;
  for (int j = threadIdx.x; j < kSLOT; j += 256) dst[j] = lp[j];
}

// ---------------------------------------------------------------------------
__global__ __launch_bounds__(256) void reduceP_kernel(
    const float* __restrict__ PB, float* __restrict__ P)
{
  int j = blockIdx.x * 256 + threadIdx.x;
  if (j >= kPSZ) return;
  int et = j / kSLOT;
  int jj = j - et * kSLOT;
  const float* base = PB + (long long)et * kNB * kSLOT + jj;
  float s = 0.f;
  int b = 0;
  for (; b + 8 <= kNB; b += 8) {
    float v0 = base[(long long)(b + 0) * kSLOT];
    float v1 = base[(long long)(b + 1) * kSLOT];
    float v2 = base[(long long)(b + 2) * kSLOT];
    float v3 = base[(long long)(b + 3) * kSLOT];
    float v4 = base[(long long)(b + 4) * kSLOT];
    float v5 = base[(long long)(b + 5) * kSLOT];
    float v6 = base[(long long)(b + 6) * kSLOT];
    float v7 = base[(long long)(b + 7) * kSLOT];
    s += ((v0 + v1) + (v2 + v3)) + ((v4 + v5) + (v6 + v7));
  }
  for (; b < kNB; ++b) s += base[(long long)b * kSLOT];
  P[j] = s;
}

// ---------------------------------------------------------------------------
__device__ __forceinline__ int lowb(const int* a, int n, int v) {
  int lo = 0, hi = n;
  while (lo < hi) { int mid = (lo + hi) >> 1; if (a[mid] < v) lo = mid + 1; else hi = mid; }
  return lo;
}

__global__ __launch_bounds__(128) void finalize_kernel(
    const int* __restrict__ bt, const int* __restrict__ brv, const int* __restrict__ br,
    const float* __restrict__ xp,
    const float* __restrict__ fc1W, const float* __restrict__ fc1b,
    const float* __restrict__ fc2W, const float* __restrict__ fc2b,
    const float* __restrict__ b_rv2t, const float* __restrict__ b_r2t,
    const float* __restrict__ b_t2rv, const float* __restrict__ b_r2rv,
    const float* __restrict__ b_rv2r, const float* __restrict__ b_t2r,
    const float* __restrict__ Cws, const float* __restrict__ P,
    float* __restrict__ xcat)
{
  int b = blockIdx.x, tid = threadIdx.x;
  __shared__ float xps[64];
  __shared__ float p1s[128];
  __shared__ int cnts[3];
  if (tid < 64) xps[tid] = xp[b * 64 + tid];
  if (tid < 3) {
    const int* ba = (tid == 0) ? bt : (tid == 1 ? brv : br);
    int N = (tid == 0) ? kNT : (tid == 1 ? kNRV : kNR);
    cnts[tid] = lowb(ba, N, b + 1) - lowb(ba, N, b);
  }
  __syncthreads();
  float a = fc1b[tid];
  for (int k = 0; k < 64; ++k) a += xps[k] * fc1W[k * 128 + tid];
  p1s[tid] = fmaxf(a, 0.f);
  __syncthreads();
  float a2 = fc2b[tid];
  for (int k = 0; k < 128; ++k) a2 += p1s[k] * fc2W[k * 128 + tid];
  xcat[b * 512 + 384 + tid] = fmaxf(a2, 0.f);
  const int etA[3] = {0, 1, 3}, etB[3] = {5, 2, 4};
  const int KAv[3] = {13, 8, 13}, KBv[3] = {4, 4, 8};
  for (int t3 = 0; t3 < 3; ++t3) {
    int eA = etA[t3], eB = etB[t3];
    const float* CA = Cws + eA * 2176;
    const float* CB = Cws + eB * 2176;
    const float* pA = P + eA * kSLOT;   // [k*64 + b] layout
    const float* pB = P + eB * kSLOT;
    float cA = pA[1024 + b];
    float cB = pB[1024 + b];
    float v = cA * CA[2048 + tid] + cB * CB[2048 + tid];
    for (int k = 0; k < KAv[t3]; ++k) v += pA[k * 64 + b] * CA[k * 128 + tid];
    for (int k = 0; k < KBv[t3]; ++k) v += pB[k * 64 + b] * CB[k * 128 + tid];
    float cnt = (float)max(cnts[t3], 1);
    const float* bb1 = (t3 == 0) ? b_rv2t : (t3 == 1 ? b_t2rv : b_rv2r);
    const float* bb2 = (t3 == 0) ? b_r2t  : (t3 == 1 ? b_r2rv : b_t2r);
    xcat[b * 512 + t3 * 128 + tid] = v / cnt + bb1[tid] + bb2[tid];
  }
}

// ---------------------------------------------------------------------------
__global__ __launch_bounds__(256) void out_kernel(
    const float* __restrict__ xcat, const float* __restrict__ outW,
    const float* __restrict__ outb, float* __restrict__ out)
{
  int g = blockIdx.x * 256 + threadIdx.x;   // 64*512
  int r = g >> 9, c = g & 511;
  const float* xr = xcat + r * 512;
  float acc = outb[c];
  for (int k = 0; k < 512; ++k) acc += xr[k] * outW[k * 512 + c];
  out[g] = acc;
}

// ---------------------------------------------------------------------------
extern "C" void kernel_launch(void* const* d_in, const int* in_sizes, int n_in,
                              void* d_out, int out_size, void* d_ws, size_t ws_size,
                              hipStream_t stream) {
  const float* x_tile   = (const float*)d_in[0];
  const float* x_rv     = (const float*)d_in[1];
  const float* x_road   = (const float*)d_in[2];
  const float* x_player = (const float*)d_in[3];
  const float* enc_t_W  = (const float*)d_in[4];
  const float* enc_t_b  = (const float*)d_in[5];
  const float* enc_rv_W = (const float*)d_in[6];
  const float* enc_rv_b = (const float*)d_in[7];
  const float* enc_r_W  = (const float*)d_in[8];
  const float* enc_r_b  = (const float*)d_in[9];
  const float* W[6]; const float* As[6]; const float* Ad[6]; const float* Bb[6];
  for (int et = 0; et < 6; ++et) {
    W[et]  = (const float*)d_in[10 + 4 * et];
    As[et] = (const float*)d_in[11 + 4 * et];
    Ad[et] = (const float*)d_in[12 + 4 * et];
    Bb[et] = (const float*)d_in[13 + 4 * et];
  }
  const float* fc1W = (const float*)d_in[34];
  const float* fc1b = (const float*)d_in[35];
  const float* fc2W = (const float*)d_in[36];
  const float* fc2b = (const float*)d_in[37];
  const float* outW = (const float*)d_in[38];
  const float* outb = (const float*)d_in[39];
  const int* esrc[6]; const int* edst[6];
  for (int et = 0; et < 6; ++et) {
    esrc[et] = (const int*)d_in[40 + 2 * et];
    edst[et] = (const int*)d_in[41 + 2 * et];
  }
  const int* batch_t  = (const int*)d_in[52];
  const int* batch_rv = (const int*)d_in[53];
  const int* batch_r  = (const int*)d_in[54];

  float* wsF = (float*)d_ws;
  float* Cws  = wsF + OFF_C;
  float* vsw  = wsF + OFF_VS;
  float* vdw  = wsF + OFF_VD;
  float* P    = wsF + OFF_P;
  float* xcat = wsF + OFF_XCAT;
  float* LS   = wsF + OFF_LS;
  float* LD   = wsF + OFF_LD;
  float* PB   = wsF + OFF_PB;        // aliases LS/LD (dead after passA)
  _Float16* W16 = (_Float16*)(wsF + OFF_W16);
  float2* DR2 = (float2*)(wsF + OFF_DR2);
  float* DR2f = wsF + OFF_DR2;
  _Float16* XR = (_Float16*)(wsF + OFF_XR);
  float* out  = (float*)d_out;

  precompute_kernel<<<6, 256, 0, stream>>>(
      enc_t_W, enc_t_b, enc_rv_W, enc_rv_b, enc_r_W, enc_r_b,
      W[0], As[0], Ad[0], W[1], As[1], Ad[1], W[2], As[2], Ad[2],
      W[3], As[3], Ad[3], W[4], As[4], Ad[4], W[5], As[5], Ad[5],
      Cws, vsw, vdw);

  prep_kernel<<<(kNT + kNRV + kNR + 255) / 256, 256, 0, stream>>>(
      x_tile, x_rv, x_road, batch_t, batch_rv, batch_r, vsw, vdw,
      LS, LD, DR2, XR);

  passA_kernel<<<(kTOTE + 255) / 256, 256, 0, stream>>>(
      esrc[0], esrc[1], esrc[2], esrc[3], esrc[4], esrc[5],
      edst[0], edst[1], edst[2], edst[3], edst[4], edst[5],
      LS, LD, DR2f, W16);

  passB_kernel<<<6 * kNB, 256, 0, stream>>>(
      esrc[0], esrc[1], esrc[2], esrc[3], esrc[4], esrc[5],
      edst[0], edst[1], edst[2], edst[3], edst[4], edst[5],
      W16, DR2, XR, PB);

  reduceP_kernel<<<(kPSZ + 255) / 256, 256, 0, stream>>>(PB, P);

  finalize_kernel<<<64, 128, 0, stream>>>(
      batch_t, batch_rv, batch_r, x_player,
      fc1W, fc1b, fc2W, fc2b,
      Bb[0], Bb[5], Bb[1], Bb[2], Bb[3], Bb[4],
      Cws, P, xcat);

  out_kernel<<<128, 256, 0, stream>>>(xcat, outW, outb, out);

  (void)in_sizes; (void)n_in; (void)out_size; (void)ws_size;
}